// Round 12
// baseline (284.456 us; speedup 1.0000x reference)
//
#include <hip/hip_runtime.h>
#include <hip/hip_bf16.h>

#define NN    50000
#define CC    4
#define NNZV  800000
#define TOTE  (CC * NNZV)          // 3,200,000 edges
#define NWG   1024                 // cscatter blocks (256 per category, exact)
#define EPW   (TOTE / NWG)         // 3125 edges per block
#define NFB   782                  // fine dst buckets (dst >> 6), 64 dsts each
#define NPART 8                    // virtual partitions of gcur (blockIdx % 8)
#define RCAPV 768                  // records per (bucket, partition) region
#define BCAP  (NPART * RCAPV)      // 6144 records per bucket max
#define NRB   782                  // ceil(50000/64) row blocks for dense stages
#define NXB   782                  // X->bf16 convert blocks (4096 elems each)
#define NPK   21                   // pack blocks (merged into fused grid)

using bf16 = __hip_bfloat16;
typedef short short8 __attribute__((ext_vector_type(8)));
typedef float f32x4  __attribute__((ext_vector_type(4)));
typedef unsigned short u16x8 __attribute__((ext_vector_type(8)));

__device__ __forceinline__ float bfu2f(unsigned short u) {
    union { unsigned int i; float f; } v;
    v.i = ((unsigned int)u) << 16;
    return v.f;
}
__device__ __forceinline__ float blo(unsigned int u) {
    union { unsigned int i; float f; } v;
    v.i = u << 16;
    return v.f;
}
__device__ __forceinline__ float bhi(unsigned int u) {
    union { unsigned int i; float f; } v;
    v.i = u & 0xFFFF0000u;
    return v.f;
}
__device__ __forceinline__ float cvt(float x) { return x; }
__device__ __forceinline__ float cvt(bf16 x)  { return __bfloat162float(x); }
__device__ __forceinline__ unsigned short tobits(float x) {
    bf16 t = __float2bfloat16(x);
    return *(unsigned short*)&t;
}

// ---------------------------------------------------------------------------
// Inline dtype detection (per-block preamble; logic proven rounds 2-9).
// ---------------------------------------------------------------------------
__device__ __forceinline__ void detect_flags(const unsigned int* __restrict__ Xw,
                                             const unsigned int* __restrict__ Aw,
                                             int* dcnt, int& f32f, int& i64f) {
    const int t = threadIdx.x, nthr = blockDim.x;
    if (t < 2) dcnt[t] = 0;
    __syncthreads();
    int c1 = 0;
    for (int i = t; i < 1024; i += nthr) {
        unsigned b = (Xw[i] >> 7) & 0xFF;
        if (b >= 118 && b <= 134) c1++;
    }
    if (c1) atomicAdd(&dcnt[0], c1);
    if (t < 128) { if (Aw[2 * t + 1] == 0) atomicAdd(&dcnt[1], 1); }
    __syncthreads();
    f32f = (dcnt[0] < 512) ? 1 : 0;
    i64f = (dcnt[1] >= 96) ? 1 : 0;
    __syncthreads();
}

// ---------------------------------------------------------------------------
// pack_body: Wfold = Ws_c @ W0_c (projection folded into Linear0), Wb1,
// biases. Runs as the last NPK blocks of fused_kernel.
// ---------------------------------------------------------------------------
template<typename TF>
__device__ __forceinline__ void pack_body(const TF* __restrict__ W0, const TF* __restrict__ W1,
                                          const TF* __restrict__ Ws, const TF* __restrict__ b0,
                                          const TF* __restrict__ b1,
                                          unsigned short* __restrict__ Wb,
                                          unsigned short* __restrict__ Wb1,
                                          float* __restrict__ bias0, float* __restrict__ bias1,
                                          int trip) {
    const int lane = trip & 63;
    const int q = lane >> 4, cI = lane & 15;
    if (trip < 4096) {
        const int k0 = trip >> 9, t8 = (trip >> 6) & 7;
        const int kbase = k0 * 32 + q * 8;      // 8 consecutive k, same c-block
        const int col   = t8 * 16 + cI;
        const int c     = kbase >> 6;
        float w0c[64];
        #pragma unroll
        for (int g = 0; g < 64; ++g)
            w0c[g] = cvt(W0[(size_t)(c * 64 + g) * 128 + col]);
        #pragma unroll
        for (int j = 0; j < 8; ++j) {
            const int f = (kbase + j) & 63;
            const TF* wsrow = Ws + ((size_t)c * 64 + f) * 64;
            float acc = 0.f;
            #pragma unroll
            for (int g = 0; g < 64; ++g)
                acc += cvt(wsrow[g]) * w0c[g];
            Wb[(size_t)trip * 8 + j] = tobits(acc);
        }
    } else if (trip < 5120) {
        const int u = trip - 4096;
        const int k0 = u >> 8, t4 = (u >> 6) & 3;
        #pragma unroll
        for (int j = 0; j < 8; ++j)
            Wb1[(size_t)u * 8 + j] =
                tobits(cvt(W1[(size_t)(k0 * 32 + q * 8 + j) * 64 + t4 * 16 + cI]));
    } else if (trip < 5248) {
        bias0[trip - 5120] = cvt(b0[trip - 5120]);
    } else if (trip < 5312) {
        bias1[trip - 5248] = cvt(b1[trip - 5248]);
    }
}

// ---------------------------------------------------------------------------
// fused_kernel: blocks [0,NWG) = cscatter (fine buckets + partitioned gcur,
// pass 1 4x unrolled), [NWG, NWG+NXB) = X -> Xb convert (sentinel row NN
// zeroed), [NWG+NXB, NWG+NXB+NPK) = weight pack.
// ---------------------------------------------------------------------------
template<typename TI>
__device__ __forceinline__ void cscat2_body(const TI* __restrict__ A,
                                            unsigned int* __restrict__ gcur,
                                            unsigned int* __restrict__ recs,
                                            unsigned int* lh, unsigned int* lrec) {
    const int w = blockIdx.x, t = threadIdx.x;
    const int v = w & (NPART - 1);
    #pragma unroll
    for (int u = 0; u < 4; ++u) lh[t + u * 256] = 0;
    __syncthreads();
    const int base   = w * EPW;
    const int c      = base / NNZV;          // constant per block
    const int eibase = base - c * NNZV;
    const TI* Ad = A + (size_t)(c * 2 + 0) * NNZV + eibase;
    const TI* As = A + (size_t)(c * 2 + 1) * NNZV + eibase;
    for (int i0 = 0; i0 + 1024 <= EPW; i0 += 1024) {
        const int ia = i0 + t;
        const int d0 = (int)Ad[ia];
        const int d1 = (int)Ad[ia + 256];
        const int d2 = (int)Ad[ia + 512];
        const int d3 = (int)Ad[ia + 768];
        const int s0 = (int)As[ia];
        const int s1 = (int)As[ia + 256];
        const int s2 = (int)As[ia + 512];
        const int s3 = (int)As[ia + 768];
        unsigned int r0 = 0xFFFFFFFFu, r1 = 0xFFFFFFFFu;
        unsigned int r2 = 0xFFFFFFFFu, r3 = 0xFFFFFFFFu;
        if ((unsigned)d0 < NN && (unsigned)s0 < NN) { r0 = ((unsigned)d0 << 16) | (unsigned)s0; atomicAdd(&lh[d0 >> 6], 1u); }
        if ((unsigned)d1 < NN && (unsigned)s1 < NN) { r1 = ((unsigned)d1 << 16) | (unsigned)s1; atomicAdd(&lh[d1 >> 6], 1u); }
        if ((unsigned)d2 < NN && (unsigned)s2 < NN) { r2 = ((unsigned)d2 << 16) | (unsigned)s2; atomicAdd(&lh[d2 >> 6], 1u); }
        if ((unsigned)d3 < NN && (unsigned)s3 < NN) { r3 = ((unsigned)d3 << 16) | (unsigned)s3; atomicAdd(&lh[d3 >> 6], 1u); }
        lrec[ia]       = r0;
        lrec[ia + 256] = r1;
        lrec[ia + 512] = r2;
        lrec[ia + 768] = r3;
    }
    {   // tail: elements [3072, 3125)
        const int ia = (EPW & ~1023) + t;
        if (ia < EPW) {
            const int dst = (int)Ad[ia];
            const int src = (int)As[ia];
            unsigned int rec = 0xFFFFFFFFu;
            if ((unsigned)dst < NN && (unsigned)src < NN) {
                rec = ((unsigned)dst << 16) | (unsigned)src;
                atomicAdd(&lh[dst >> 6], 1u);
            }
            lrec[ia] = rec;
        }
    }
    __syncthreads();
    unsigned int cl[4], sl[4];
    #pragma unroll
    for (int u = 0; u < 4; ++u) cl[u] = lh[t + u * 256];
    __syncthreads();
    #pragma unroll
    for (int u = 0; u < 4; ++u)
        sl[u] = cl[u] ? atomicAdd(&gcur[(v << 10) + t + u * 256], cl[u]) : 0u;
    #pragma unroll
    for (int u = 0; u < 4; ++u) lh[t + u * 256] = sl[u];
    __syncthreads();
    const unsigned int cb = (unsigned)c << 16;
    for (int i = t; i < EPW; i += 256) {
        const unsigned int rec = lrec[i];
        if (rec == 0xFFFFFFFFu) continue;
        const int dst = (int)(rec >> 16);
        const int b   = dst >> 6;
        const unsigned int pos = atomicAdd(&lh[b], 1u);
        if (pos < RCAPV)
            recs[((size_t)b * NPART + v) * RCAPV + pos] =
                ((unsigned)(dst & 63) << 18) | cb | (rec & 0xFFFFu);
    }
}

__device__ __forceinline__ void xconv_body(const void* __restrict__ X, int f32f,
                                           unsigned short* __restrict__ Xb, int bidx) {
    const size_t base = (size_t)bidx * 4096 + (size_t)threadIdx.x * 16;
    #pragma unroll
    for (int i = 0; i < 4; ++i) {
        const size_t off = base + (size_t)i * 4;
        if (off < (size_t)NN * 64) {
            ushort4 o;
            if (f32f) {
                const float4 v = *(const float4*)((const float*)X + off);
                o.x = tobits(v.x); o.y = tobits(v.y); o.z = tobits(v.z); o.w = tobits(v.w);
            } else {
                o = *(const ushort4*)((const unsigned short*)X + off);
            }
            *(ushort4*)(Xb + off) = o;
        } else if (off < (size_t)(NN + 1) * 64) {
            *(ushort4*)(Xb + off) = make_ushort4(0, 0, 0, 0);   // sentinel row
        }
    }
}

__global__ __launch_bounds__(256) void fused_kernel(const void* __restrict__ X,
                                                    const void* __restrict__ A,
                                                    const void* __restrict__ W0,
                                                    const void* __restrict__ W1,
                                                    const void* __restrict__ Ws,
                                                    const void* __restrict__ b0,
                                                    const void* __restrict__ b1,
                                                    unsigned short* __restrict__ Xb,
                                                    unsigned int* __restrict__ gcur,
                                                    unsigned int* __restrict__ recs,
                                                    unsigned short* __restrict__ Wb,
                                                    unsigned short* __restrict__ Wb1,
                                                    float* __restrict__ bias0,
                                                    float* __restrict__ bias1) {
    __shared__ unsigned int Su[1024 + EPW];   // lh[1024] + lrec[3125]
    __shared__ int dcnt[2];
    int f32f, i64f;
    detect_flags((const unsigned int*)X, (const unsigned int*)A, dcnt, f32f, i64f);
    if (blockIdx.x < NWG) {
        unsigned int* lh   = Su;         // 1024 u32
        unsigned int* lrec = Su + 1024;  // 3125 u32
        if (i64f) cscat2_body<long long>((const long long*)A, gcur, recs, lh, lrec);
        else      cscat2_body<int>      ((const int*)A,       gcur, recs, lh, lrec);
    } else if (blockIdx.x < NWG + NXB) {
        xconv_body(X, f32f, Xb, blockIdx.x - NWG);
    } else {
        const int trip = (blockIdx.x - (NWG + NXB)) * 256 + threadIdx.x;
        if (trip < 5312) {
            if (f32f) pack_body<float>((const float*)W0, (const float*)W1, (const float*)Ws,
                                       (const float*)b0, (const float*)b1, Wb, Wb1, bias0, bias1, trip);
            else      pack_body<bf16> ((const bf16*)W0, (const bf16*)W1, (const bf16*)Ws,
                                       (const bf16*)b0, (const bf16*)b1, Wb, Wb1, bias0, bias1, trip);
        }
    }
}

// ---------------------------------------------------------------------------
// l0_mfma (fused sort + gather + GEMM), 1024 threads / 16 waves per block.
//   A: histogram/scan/scatter into 8-padded LDS elist (pads -> row NN);
//   B: 128 x 8-lane groups, 2 segments SEQUENTIALLY (#pragma unroll 1 --
//      r10's unroll-2 interleave spilled to scratch: WRITE_SIZE 13->215 MB);
//      each lane loads 16 B (uint4 = 8 bf16) per edge, two 4-load batches
//      per 8-edge step -> <=4 uint4 live, no spill; lane-ADDRESS count
//      halves vs the 8-B scheme (cost ~ lane-addresses, r4-r10 model);
//   C: 16-wave MFMA + bias + fused BN partial sums + bf16 h store.
// ~57 KB LDS -> 2 blocks/CU (32 waves).
// ---------------------------------------------------------------------------
__global__ __launch_bounds__(1024, 8) void l0_mfma(const unsigned int* __restrict__ gcur,
                                                   const unsigned int* __restrict__ recs,
                                                   const unsigned short* __restrict__ Xb,
                                                   const unsigned short* __restrict__ Wb,
                                                   const float* __restrict__ bias0,
                                                   unsigned short* __restrict__ hO,
                                                   float* __restrict__ stats) {
    __shared__ unsigned short elist[8192];          // 16 KB, <= 7929 used
    __shared__ unsigned short Hs[64 * 264];         // 33.8 KB
    __shared__ unsigned int scnt[256], sstart[256], scur[256], send[256], ts[256];
    __shared__ unsigned int cntv[NPART];
    __shared__ float psum[128], psq[128];
    const int b = blockIdx.x, t = threadIdx.x;
    const int n0 = b * 64;
    if (t < NPART) {
        unsigned int n = gcur[(t << 10) + b];
        cntv[t] = n < RCAPV ? n : RCAPV;
    }
    if (t < 256) scnt[t] = 0;
    if (t < 128) { psum[t] = 0.f; psq[t] = 0.f; }
    __syncthreads();
    const size_t rb = (size_t)b * BCAP;
    #pragma unroll
    for (int v = 0; v < NPART; ++v) {
        if (t < (int)cntv[v])
            atomicAdd(&scnt[recs[rb + v * RCAPV + t] >> 16], 1u);
    }
    __syncthreads();
    unsigned int myp = 0;
    if (t < 256) { myp = (scnt[t] + 7u) & ~7u; ts[t] = myp; }
    __syncthreads();
    for (int off = 1; off < 256; off <<= 1) {
        unsigned int val = 0;
        if (t < 256 && t >= off) val = ts[t - off];
        __syncthreads();
        if (t < 256) ts[t] += val;
        __syncthreads();
    }
    if (t < 256) {
        const unsigned int ex = ts[t] - myp;
        sstart[t] = ex; scur[t] = ex; send[t] = ex + myp;
        for (unsigned int j = ex + scnt[t]; j < ex + myp; ++j)
            elist[j] = (unsigned short)NN;          // pad -> zero row
    }
    __syncthreads();
    #pragma unroll
    for (int v = 0; v < NPART; ++v) {
        if (t < (int)cntv[v]) {
            const unsigned int r = recs[rb + v * RCAPV + t];
            const unsigned int pos = atomicAdd(&scur[r >> 16], 1u);
            elist[pos] = (unsigned short)(r & 0xFFFFu);
        }
    }
    __syncthreads();
    // ---- Phase B: gather into Hs tile (8-lane groups, 16-B loads) ---------
    {
        const int g  = t >> 3;            // 0..127 group
        const int li = t & 7;             // lane in group
        const int g8 = li * 8;            // u16 offset within row
        const unsigned int* Xw = (const unsigned int*)Xb;
        #pragma unroll 1
        for (int s2 = 0; s2 < 2; ++s2) {
            const int seg = g * 2 + s2;                 // row = seg>>2, cat = seg&3
            const int start = (int)sstart[seg];
            const int pcnt  = (int)(send[seg] - sstart[seg]);   // multiple of 8
            float a0 = 0.f, a1 = 0.f, a2 = 0.f, a3 = 0.f;
            float a4 = 0.f, a5 = 0.f, a6 = 0.f, a7 = 0.f;
            for (int e0 = 0; e0 < pcnt; e0 += 8) {
                const u16x8 idx = *(const u16x8*)(elist + start + e0);
                {
                    const uint4 w0 = *(const uint4*)(Xw + (size_t)idx[0] * 32 + li * 4);
                    const uint4 w1 = *(const uint4*)(Xw + (size_t)idx[1] * 32 + li * 4);
                    const uint4 w2 = *(const uint4*)(Xw + (size_t)idx[2] * 32 + li * 4);
                    const uint4 w3 = *(const uint4*)(Xw + (size_t)idx[3] * 32 + li * 4);
                    a0 += blo(w0.x); a1 += bhi(w0.x); a2 += blo(w0.y); a3 += bhi(w0.y);
                    a4 += blo(w0.z); a5 += bhi(w0.z); a6 += blo(w0.w); a7 += bhi(w0.w);
                    a0 += blo(w1.x); a1 += bhi(w1.x); a2 += blo(w1.y); a3 += bhi(w1.y);
                    a4 += blo(w1.z); a5 += bhi(w1.z); a6 += blo(w1.w); a7 += bhi(w1.w);
                    a0 += blo(w2.x); a1 += bhi(w2.x); a2 += blo(w2.y); a3 += bhi(w2.y);
                    a4 += blo(w2.z); a5 += bhi(w2.z); a6 += blo(w2.w); a7 += bhi(w2.w);
                    a0 += blo(w3.x); a1 += bhi(w3.x); a2 += blo(w3.y); a3 += bhi(w3.y);
                    a4 += blo(w3.z); a5 += bhi(w3.z); a6 += blo(w3.w); a7 += bhi(w3.w);
                }
                {
                    const uint4 w4 = *(const uint4*)(Xw + (size_t)idx[4] * 32 + li * 4);
                    const uint4 w5 = *(const uint4*)(Xw + (size_t)idx[5] * 32 + li * 4);
                    const uint4 w6 = *(const uint4*)(Xw + (size_t)idx[6] * 32 + li * 4);
                    const uint4 w7 = *(const uint4*)(Xw + (size_t)idx[7] * 32 + li * 4);
                    a0 += blo(w4.x); a1 += bhi(w4.x); a2 += blo(w4.y); a3 += bhi(w4.y);
                    a4 += blo(w4.z); a5 += bhi(w4.z); a6 += blo(w4.w); a7 += bhi(w4.w);
                    a0 += blo(w5.x); a1 += bhi(w5.x); a2 += blo(w5.y); a3 += bhi(w5.y);
                    a4 += blo(w5.z); a5 += bhi(w5.z); a6 += blo(w5.w); a7 += bhi(w5.w);
                    a0 += blo(w6.x); a1 += bhi(w6.x); a2 += blo(w6.y); a3 += bhi(w6.y);
                    a4 += blo(w6.z); a5 += bhi(w6.z); a6 += blo(w6.w); a7 += bhi(w6.w);
                    a0 += blo(w7.x); a1 += bhi(w7.x); a2 += blo(w7.y); a3 += bhi(w7.y);
                    a4 += blo(w7.z); a5 += bhi(w7.z); a6 += blo(w7.w); a7 += bhi(w7.w);
                }
            }
            u16x8 o;
            o[0] = tobits(a0); o[1] = tobits(a1); o[2] = tobits(a2); o[3] = tobits(a3);
            o[4] = tobits(a4); o[5] = tobits(a5); o[6] = tobits(a6); o[7] = tobits(a7);
            const int row = seg >> 2, c = seg & 3;
            *(u16x8*)(&Hs[row * 264 + c * 64 + g8]) = o;
        }
    }
    __syncthreads();
    // ---- Phase C: 16-wave MFMA + bias + BN + store ------------------------
    const int w = t >> 6, lane = t & 63;
    const int q = lane >> 4, cI = lane & 15;
    const int wr = w & 3;             // row group (16 rows)
    const int wc = w >> 2;            // col group (32 cols)
    f32x4 acc[2];
    #pragma unroll
    for (int i = 0; i < 2; ++i) acc[i] = (f32x4){0.f, 0.f, 0.f, 0.f};
    const unsigned short* arow = &Hs[(wr * 16 + cI) * 264 + q * 8];
    #pragma unroll
    for (int k0 = 0; k0 < 8; ++k0) {
        short8 a = *(const short8*)(arow + k0 * 32);
        #pragma unroll
        for (int t4 = 0; t4 < 2; ++t4) {
            const int t8 = wc * 2 + t4;
            short8 bb = *(const short8*)(Wb + ((size_t)(k0 * 8 + t8) * 64 + lane) * 8);
            acc[t4] = __builtin_amdgcn_mfma_f32_16x16x32_bf16(a, bb, acc[t4], 0, 0, 0);
        }
    }
    __syncthreads();
    const int rloc  = wr * 16 + q * 4;
    const int rbase = n0 + rloc;
    #pragma unroll
    for (int t4 = 0; t4 < 2; ++t4) {
        const int col = (wc * 2 + t4) * 16 + cI;
        const float bc = bias0[col];
        float s = 0.f, qq = 0.f;
        #pragma unroll
        for (int r = 0; r < 4; ++r) {
            float v = acc[t4][r] + bc;
            Hs[(rloc + r) * 136 + col] = tobits(v);
            if (rbase + r >= NN) v = 0.f;
            s += v; qq += v * v;
        }
        s  += __shfl_xor(s, 16, 64);  s  += __shfl_xor(s, 32, 64);
        qq += __shfl_xor(qq, 16, 64); qq += __shfl_xor(qq, 32, 64);
        if (q == 0) { atomicAdd(&psum[col], s); atomicAdd(&psq[col], qq); }
    }
    __syncthreads();
    if (t < 128) { atomicAdd(&stats[t], psum[t]); atomicAdd(&stats[128 + t], psq[t]); }
    {
        const int row  = t >> 4;
        const int col0 = (t & 15) * 8;
        const int grow = n0 + row;
        if (grow < NN) {
            *(ushort4*)(hO + (size_t)grow * 128 + col0)     = *(ushort4*)(&Hs[row * 136 + col0]);
            *(ushort4*)(hO + (size_t)grow * 128 + col0 + 4) = *(ushort4*)(&Hs[row * 136 + col0 + 4]);
        }
    }
}

// ---------------------------------------------------------------------------
// l1_mfma: out = elu(bn(h)) @ W1 + b1; bn-coef computed in preamble.
// ---------------------------------------------------------------------------
__global__ __launch_bounds__(256) void l1_mfma(const void* __restrict__ X,
                                               const void* __restrict__ A,
                                               const unsigned short* __restrict__ hg,
                                               const float* __restrict__ stats,
                                               const void* __restrict__ gamma,
                                               const void* __restrict__ beta,
                                               const unsigned short* __restrict__ Wb1,
                                               const float* __restrict__ bias1,
                                               void* __restrict__ outv) {
    __shared__ unsigned short Es[64 * 136];
    __shared__ float coefL[256];
    __shared__ int dcnt[2];
    int f32f, i64f;
    detect_flags((const unsigned int*)X, (const unsigned int*)A, dcnt, f32f, i64f);
    const int t = threadIdx.x;
    if (t < 128) {
        const float invN = 1.0f / (float)NN;
        const float mean = stats[t] * invN;
        const float var  = stats[128 + t] * invN - mean * mean;
        const float inv  = rsqrtf(var + 1e-5f);
        const float ga = f32f ? ((const float*)gamma)[t] : cvt(((const bf16*)gamma)[t]);
        const float be = f32f ? ((const float*)beta)[t]  : cvt(((const bf16*)beta)[t]);
        const float a = ga * inv;
        coefL[t] = a;
        coefL[128 + t] = be - mean * a;
    }
    __syncthreads();
    const int n0 = blockIdx.x * 64;
    #pragma unroll
    for (int i = 0; i < 8; ++i) {
        const int r = (t >> 5) + i * 8;
        const int k = (t & 31) * 4;
        const int row = n0 + r;
        ushort4 o = make_ushort4(0, 0, 0, 0);
        if (row < NN) {
            ushort4 v = *(const ushort4*)(hg + (size_t)row * 128 + k);
            float f0 = coefL[k + 0] * bfu2f(v.x) + coefL[128 + k + 0];
            float f1 = coefL[k + 1] * bfu2f(v.y) + coefL[128 + k + 1];
            float f2 = coefL[k + 2] * bfu2f(v.z) + coefL[128 + k + 2];
            float f3 = coefL[k + 3] * bfu2f(v.w) + coefL[128 + k + 3];
            f0 = f0 > 0.f ? f0 : expm1f(f0);
            f1 = f1 > 0.f ? f1 : expm1f(f1);
            f2 = f2 > 0.f ? f2 : expm1f(f2);
            f3 = f3 > 0.f ? f3 : expm1f(f3);
            o.x = tobits(f0); o.y = tobits(f1); o.z = tobits(f2); o.w = tobits(f3);
        }
        *(ushort4*)(&Es[r * 136 + k]) = o;
    }
    __syncthreads();
    const int w = t >> 6, lane = t & 63;
    const int q = lane >> 4, cI = lane & 15;
    f32x4 acc[4];
    #pragma unroll
    for (int i = 0; i < 4; ++i) acc[i] = (f32x4){0.f, 0.f, 0.f, 0.f};
    const unsigned short* arow = &Es[(w * 16 + cI) * 136 + q * 8];
    #pragma unroll
    for (int k0 = 0; k0 < 4; ++k0) {
        short8 a = *(const short8*)(arow + k0 * 32);
        #pragma unroll
        for (int t4 = 0; t4 < 4; ++t4) {
            short8 b = *(const short8*)(Wb1 + ((size_t)(k0 * 4 + t4) * 64 + lane) * 8);
            acc[t4] = __builtin_amdgcn_mfma_f32_16x16x32_bf16(a, b, acc[t4], 0, 0, 0);
        }
    }
    __syncthreads();
    float* ot = (float*)Es;                   // 64 x 68 float tile
    const int rloc = w * 16 + q * 4;
    #pragma unroll
    for (int t4 = 0; t4 < 4; ++t4) {
        const int col = t4 * 16 + cI;
        const float bc = bias1[col];
        #pragma unroll
        for (int r = 0; r < 4; ++r)
            ot[(rloc + r) * 68 + col] = acc[t4][r] + bc;
    }
    __syncthreads();
    #pragma unroll
    for (int i = 0; i < 4; ++i) {
        const int m    = t + i * 256;
        const int row  = m >> 4;
        const int col0 = (m & 15) * 4;
        const int grow = n0 + row;
        if (grow >= NN) continue;
        const float f0 = ot[row * 68 + col0 + 0];
        const float f1 = ot[row * 68 + col0 + 1];
        const float f2 = ot[row * 68 + col0 + 2];
        const float f3 = ot[row * 68 + col0 + 3];
        if (f32f) {
            float4 o; o.x = f0; o.y = f1; o.z = f2; o.w = f3;
            *(float4*)((float*)outv + (size_t)grow * 64 + col0) = o;
        } else {
            ushort4 o;
            o.x = tobits(f0); o.y = tobits(f1); o.z = tobits(f2); o.w = tobits(f3);
            *(ushort4*)((unsigned short*)outv + (size_t)grow * 64 + col0) = o;
        }
    }
}

// ---------------------------------------------------------------------------
// Workspace layout (bytes):
//   Xb       : [N+1,64] bf16    @ 0             6,400,256 (row NN = zeros)
//   h        : [N,128]  bf16    @ 6,400,256    12,800,000
//   recs     : [782*8*768] u32  @ 19,200,256   19,218,432
//   stats    : [256] f32        @ 38,418,688        1,024  -- zeroed by memset
//   gcur     : [8192] u32       @ 38,419,712       32,768  -- zeroed by memset
//   Wb       : u16 (Wfold)      @ 38,452,480       65,536
//   Wb1      : u16              @ 38,518,016       16,384
//   bias0    : f32[128]         @ 38,534,400          512
//   bias1    : f32[64]          @ 38,534,912          256
// total 38,535,168 B (~36.7 MiB)
// ---------------------------------------------------------------------------
extern "C" void kernel_launch(void* const* d_in, const int* in_sizes, int n_in,
                              void* d_out, int out_size, void* d_ws, size_t ws_size,
                              hipStream_t stream) {
    const void* A     = d_in[0];
    const void* X     = d_in[1];
    const void* Ws    = d_in[2];
    const void* W0    = d_in[3];
    const void* b0    = d_in[4];
    const void* gamma = d_in[5];
    const void* beta  = d_in[6];
    const void* W1    = d_in[7];
    const void* b1    = d_in[8];

    char* ws = (char*)d_ws;
    unsigned short* Xb       = (unsigned short*)(ws);
    unsigned short* h        = (unsigned short*)(ws + 6400256);
    unsigned int*   recs     = (unsigned int*)  (ws + 19200256);
    float*          stats    = (float*)         (ws + 38418688);
    unsigned int*   gcur     = (unsigned int*)  (ws + 38419712);
    unsigned short* Wb       = (unsigned short*)(ws + 38452480);
    unsigned short* Wb1      = (unsigned short*)(ws + 38518016);
    float*          bias0    = (float*)         (ws + 38534400);
    float*          bias1    = (float*)         (ws + 38534912);

    hipMemsetAsync(stats, 0, 33792, stream);       // stats[256] + gcur[8192]
    fused_kernel<<<NWG + NXB + NPK, 256, 0, stream>>>(X, A, W0, W1, Ws, b0, b1,
                                                      Xb, gcur, recs,
                                                      Wb, Wb1, bias0, bias1);
    l0_mfma     <<<NRB, 1024, 0, stream>>>(gcur, recs, Xb, Wb, bias0, h, stats);
    l1_mfma     <<<NRB, 256, 0, stream>>>(X, A, h, stats, gamma, beta, Wb1, bias1, d_out);
}

// Round 13
// 220.210 us; speedup vs baseline: 1.2917x; 1.2917x over previous
//
#include <hip/hip_runtime.h>
#include <hip/hip_bf16.h>

#define NN    50000
#define CC    4
#define NNZV  800000
#define TOTE  (CC * NNZV)          // 3,200,000 edges
#define NWG   1024                 // cscatter blocks (256 per category, exact)
#define EPW   (TOTE / NWG)         // 3125 edges per block
#define NFB   782                  // fine dst buckets (dst >> 6), 64 dsts each
#define NPART 8                    // virtual partitions of gcur (blockIdx % 8)
#define RCAPV 768                  // records per (bucket, partition) region
#define BCAP  (NPART * RCAPV)      // 6144 records per bucket max
#define NRB   782                  // ceil(50000/64) row blocks for dense stages
#define NXB   782                  // X->bf16 convert blocks (4096 elems each)
#define NPK   21                   // pack blocks (merged into fused grid)

using bf16 = __hip_bfloat16;
typedef short short8 __attribute__((ext_vector_type(8)));
typedef float f32x4  __attribute__((ext_vector_type(4)));
typedef unsigned short u16x8 __attribute__((ext_vector_type(8)));

__device__ __forceinline__ float bfu2f(unsigned short u) {
    union { unsigned int i; float f; } v;
    v.i = ((unsigned int)u) << 16;
    return v.f;
}
__device__ __forceinline__ float cvt(float x) { return x; }
__device__ __forceinline__ float cvt(bf16 x)  { return __bfloat162float(x); }
__device__ __forceinline__ unsigned short tobits(float x) {
    bf16 t = __float2bfloat16(x);
    return *(unsigned short*)&t;
}

// ---------------------------------------------------------------------------
// Inline dtype detection (per-block preamble; logic proven rounds 2-9).
// ---------------------------------------------------------------------------
__device__ __forceinline__ void detect_flags(const unsigned int* __restrict__ Xw,
                                             const unsigned int* __restrict__ Aw,
                                             int* dcnt, int& f32f, int& i64f) {
    const int t = threadIdx.x, nthr = blockDim.x;
    if (t < 2) dcnt[t] = 0;
    __syncthreads();
    int c1 = 0;
    for (int i = t; i < 1024; i += nthr) {
        unsigned b = (Xw[i] >> 7) & 0xFF;
        if (b >= 118 && b <= 134) c1++;
    }
    if (c1) atomicAdd(&dcnt[0], c1);
    if (t < 128) { if (Aw[2 * t + 1] == 0) atomicAdd(&dcnt[1], 1); }
    __syncthreads();
    f32f = (dcnt[0] < 512) ? 1 : 0;
    i64f = (dcnt[1] >= 96) ? 1 : 0;
    __syncthreads();
}

// ---------------------------------------------------------------------------
// pack_body: Wfold = Ws_c @ W0_c (projection folded into Linear0), Wb1,
// biases. Runs as the last NPK blocks of fused_kernel (outputs consumed
// only by l0/l1). Zeroing of stats+gcur via hipMemsetAsync.
// ---------------------------------------------------------------------------
template<typename TF>
__device__ __forceinline__ void pack_body(const TF* __restrict__ W0, const TF* __restrict__ W1,
                                          const TF* __restrict__ Ws, const TF* __restrict__ b0,
                                          const TF* __restrict__ b1,
                                          unsigned short* __restrict__ Wb,
                                          unsigned short* __restrict__ Wb1,
                                          float* __restrict__ bias0, float* __restrict__ bias1,
                                          int trip) {
    const int lane = trip & 63;
    const int q = lane >> 4, cI = lane & 15;
    if (trip < 4096) {
        const int k0 = trip >> 9, t8 = (trip >> 6) & 7;
        const int kbase = k0 * 32 + q * 8;      // 8 consecutive k, same c-block
        const int col   = t8 * 16 + cI;
        const int c     = kbase >> 6;
        float w0c[64];
        #pragma unroll
        for (int g = 0; g < 64; ++g)
            w0c[g] = cvt(W0[(size_t)(c * 64 + g) * 128 + col]);
        #pragma unroll
        for (int j = 0; j < 8; ++j) {
            const int f = (kbase + j) & 63;
            const TF* wsrow = Ws + ((size_t)c * 64 + f) * 64;
            float acc = 0.f;
            #pragma unroll
            for (int g = 0; g < 64; ++g)
                acc += cvt(wsrow[g]) * w0c[g];
            Wb[(size_t)trip * 8 + j] = tobits(acc);
        }
    } else if (trip < 5120) {
        const int u = trip - 4096;
        const int k0 = u >> 8, t4 = (u >> 6) & 3;
        #pragma unroll
        for (int j = 0; j < 8; ++j)
            Wb1[(size_t)u * 8 + j] =
                tobits(cvt(W1[(size_t)(k0 * 32 + q * 8 + j) * 64 + t4 * 16 + cI]));
    } else if (trip < 5248) {
        bias0[trip - 5120] = cvt(b0[trip - 5120]);
    } else if (trip < 5312) {
        bias1[trip - 5248] = cvt(b1[trip - 5248]);
    }
}

// ---------------------------------------------------------------------------
// fused_kernel: blocks [0,NWG) = cscatter (fine buckets + partitioned gcur,
// pass 1 4x unrolled), [NWG, NWG+NXB) = X -> Xb convert (sentinel row NN
// zeroed), [NWG+NXB, NWG+NXB+NPK) = weight pack.
// ---------------------------------------------------------------------------
template<typename TI>
__device__ __forceinline__ void cscat2_body(const TI* __restrict__ A,
                                            unsigned int* __restrict__ gcur,
                                            unsigned int* __restrict__ recs,
                                            unsigned int* lh, unsigned int* lrec) {
    const int w = blockIdx.x, t = threadIdx.x;
    const int v = w & (NPART - 1);
    #pragma unroll
    for (int u = 0; u < 4; ++u) lh[t + u * 256] = 0;
    __syncthreads();
    const int base   = w * EPW;
    const int c      = base / NNZV;          // constant per block
    const int eibase = base - c * NNZV;
    const TI* Ad = A + (size_t)(c * 2 + 0) * NNZV + eibase;
    const TI* As = A + (size_t)(c * 2 + 1) * NNZV + eibase;
    for (int i0 = 0; i0 + 1024 <= EPW; i0 += 1024) {
        const int ia = i0 + t;
        const int d0 = (int)Ad[ia];
        const int d1 = (int)Ad[ia + 256];
        const int d2 = (int)Ad[ia + 512];
        const int d3 = (int)Ad[ia + 768];
        const int s0 = (int)As[ia];
        const int s1 = (int)As[ia + 256];
        const int s2 = (int)As[ia + 512];
        const int s3 = (int)As[ia + 768];
        unsigned int r0 = 0xFFFFFFFFu, r1 = 0xFFFFFFFFu;
        unsigned int r2 = 0xFFFFFFFFu, r3 = 0xFFFFFFFFu;
        if ((unsigned)d0 < NN && (unsigned)s0 < NN) { r0 = ((unsigned)d0 << 16) | (unsigned)s0; atomicAdd(&lh[d0 >> 6], 1u); }
        if ((unsigned)d1 < NN && (unsigned)s1 < NN) { r1 = ((unsigned)d1 << 16) | (unsigned)s1; atomicAdd(&lh[d1 >> 6], 1u); }
        if ((unsigned)d2 < NN && (unsigned)s2 < NN) { r2 = ((unsigned)d2 << 16) | (unsigned)s2; atomicAdd(&lh[d2 >> 6], 1u); }
        if ((unsigned)d3 < NN && (unsigned)s3 < NN) { r3 = ((unsigned)d3 << 16) | (unsigned)s3; atomicAdd(&lh[d3 >> 6], 1u); }
        lrec[ia]       = r0;
        lrec[ia + 256] = r1;
        lrec[ia + 512] = r2;
        lrec[ia + 768] = r3;
    }
    {   // tail: elements [3072, 3125)
        const int ia = (EPW & ~1023) + t;
        if (ia < EPW) {
            const int dst = (int)Ad[ia];
            const int src = (int)As[ia];
            unsigned int rec = 0xFFFFFFFFu;
            if ((unsigned)dst < NN && (unsigned)src < NN) {
                rec = ((unsigned)dst << 16) | (unsigned)src;
                atomicAdd(&lh[dst >> 6], 1u);
            }
            lrec[ia] = rec;
        }
    }
    __syncthreads();
    unsigned int cl[4], sl[4];
    #pragma unroll
    for (int u = 0; u < 4; ++u) cl[u] = lh[t + u * 256];
    __syncthreads();
    #pragma unroll
    for (int u = 0; u < 4; ++u)
        sl[u] = cl[u] ? atomicAdd(&gcur[(v << 10) + t + u * 256], cl[u]) : 0u;
    #pragma unroll
    for (int u = 0; u < 4; ++u) lh[t + u * 256] = sl[u];
    __syncthreads();
    const unsigned int cb = (unsigned)c << 16;
    for (int i = t; i < EPW; i += 256) {
        const unsigned int rec = lrec[i];
        if (rec == 0xFFFFFFFFu) continue;
        const int dst = (int)(rec >> 16);
        const int b   = dst >> 6;
        const unsigned int pos = atomicAdd(&lh[b], 1u);
        if (pos < RCAPV)
            recs[((size_t)b * NPART + v) * RCAPV + pos] =
                ((unsigned)(dst & 63) << 18) | cb | (rec & 0xFFFFu);
    }
}

__device__ __forceinline__ void xconv_body(const void* __restrict__ X, int f32f,
                                           unsigned short* __restrict__ Xb, int bidx) {
    const size_t base = (size_t)bidx * 4096 + (size_t)threadIdx.x * 16;
    #pragma unroll
    for (int i = 0; i < 4; ++i) {
        const size_t off = base + (size_t)i * 4;
        if (off < (size_t)NN * 64) {
            ushort4 o;
            if (f32f) {
                const float4 v = *(const float4*)((const float*)X + off);
                o.x = tobits(v.x); o.y = tobits(v.y); o.z = tobits(v.z); o.w = tobits(v.w);
            } else {
                o = *(const ushort4*)((const unsigned short*)X + off);
            }
            *(ushort4*)(Xb + off) = o;
        } else if (off < (size_t)(NN + 1) * 64) {
            *(ushort4*)(Xb + off) = make_ushort4(0, 0, 0, 0);   // sentinel row
        }
    }
}

__global__ __launch_bounds__(256) void fused_kernel(const void* __restrict__ X,
                                                    const void* __restrict__ A,
                                                    const void* __restrict__ W0,
                                                    const void* __restrict__ W1,
                                                    const void* __restrict__ Ws,
                                                    const void* __restrict__ b0,
                                                    const void* __restrict__ b1,
                                                    unsigned short* __restrict__ Xb,
                                                    unsigned int* __restrict__ gcur,
                                                    unsigned int* __restrict__ recs,
                                                    unsigned short* __restrict__ Wb,
                                                    unsigned short* __restrict__ Wb1,
                                                    float* __restrict__ bias0,
                                                    float* __restrict__ bias1) {
    __shared__ unsigned int Su[1024 + EPW];   // lh[1024] + lrec[3125]
    __shared__ int dcnt[2];
    int f32f, i64f;
    detect_flags((const unsigned int*)X, (const unsigned int*)A, dcnt, f32f, i64f);
    if (blockIdx.x < NWG) {
        unsigned int* lh   = Su;         // 1024 u32
        unsigned int* lrec = Su + 1024;  // 3125 u32
        if (i64f) cscat2_body<long long>((const long long*)A, gcur, recs, lh, lrec);
        else      cscat2_body<int>      ((const int*)A,       gcur, recs, lh, lrec);
    } else if (blockIdx.x < NWG + NXB) {
        xconv_body(X, f32f, Xb, blockIdx.x - NWG);
    } else {
        const int trip = (blockIdx.x - (NWG + NXB)) * 256 + threadIdx.x;
        if (trip < 5312) {
            if (f32f) pack_body<float>((const float*)W0, (const float*)W1, (const float*)Ws,
                                       (const float*)b0, (const float*)b1, Wb, Wb1, bias0, bias1, trip);
            else      pack_body<bf16> ((const bf16*)W0, (const bf16*)W1, (const bf16*)Ws,
                                       (const bf16*)b0, (const bf16*)b1, Wb, Wb1, bias0, bias1, trip);
        }
    }
}

// ---------------------------------------------------------------------------
// l0_mfma (fused sort + gather + GEMM), 1024 threads / 16 waves per block,
// ~57 KB LDS -> 2 blocks/CU (the PROVEN r5/r9 form: 85.8 us, no spill).
//   A: histogram/scan/scatter of the bucket's recs into 8-padded LDS elist;
//   B: 64 x 16-lane groups, one dst row each (4 segments), 8-B loads,
//      8-deep unroll -- at the measured random line-fetch ceiling;
//   C: 16-wave MFMA + bias + fused BN partial sums + bf16 h store.
// ---------------------------------------------------------------------------
__global__ __launch_bounds__(1024, 8) void l0_mfma(const unsigned int* __restrict__ gcur,
                                                   const unsigned int* __restrict__ recs,
                                                   const unsigned short* __restrict__ Xb,
                                                   const unsigned short* __restrict__ Wb,
                                                   const float* __restrict__ bias0,
                                                   unsigned short* __restrict__ hO,
                                                   float* __restrict__ stats) {
    __shared__ unsigned short elist[8192];          // 16 KB, <= 7929 used
    __shared__ unsigned short Hs[64 * 264];         // 33.8 KB
    __shared__ unsigned int scnt[256], sstart[256], scur[256], send[256], ts[256];
    __shared__ unsigned int cntv[NPART];
    __shared__ float psum[128], psq[128];
    const int b = blockIdx.x, t = threadIdx.x;
    const int n0 = b * 64;
    if (t < NPART) {
        unsigned int n = gcur[(t << 10) + b];
        cntv[t] = n < RCAPV ? n : RCAPV;
    }
    if (t < 256) scnt[t] = 0;
    if (t < 128) { psum[t] = 0.f; psq[t] = 0.f; }
    __syncthreads();
    const size_t rb = (size_t)b * BCAP;
    #pragma unroll
    for (int v = 0; v < NPART; ++v) {
        if (t < (int)cntv[v])
            atomicAdd(&scnt[recs[rb + v * RCAPV + t] >> 16], 1u);
    }
    __syncthreads();
    unsigned int myp = 0;
    if (t < 256) { myp = (scnt[t] + 7u) & ~7u; ts[t] = myp; }
    __syncthreads();
    for (int off = 1; off < 256; off <<= 1) {
        unsigned int val = 0;
        if (t < 256 && t >= off) val = ts[t - off];
        __syncthreads();
        if (t < 256) ts[t] += val;
        __syncthreads();
    }
    if (t < 256) {
        const unsigned int ex = ts[t] - myp;
        sstart[t] = ex; scur[t] = ex; send[t] = ex + myp;
        for (unsigned int j = ex + scnt[t]; j < ex + myp; ++j)
            elist[j] = (unsigned short)NN;          // pad -> zero row
    }
    __syncthreads();
    #pragma unroll
    for (int v = 0; v < NPART; ++v) {
        if (t < (int)cntv[v]) {
            const unsigned int r = recs[rb + v * RCAPV + t];
            const unsigned int pos = atomicAdd(&scur[r >> 16], 1u);
            elist[pos] = (unsigned short)(r & 0xFFFFu);
        }
    }
    __syncthreads();
    // ---- Phase B: gather into Hs tile (64 groups, one dst row each) -------
    {
        const int g  = t >> 4;            // 0..63 group == dst row
        const int li = t & 15;
        const int g4 = li * 4;
        #pragma unroll
        for (int s4 = 0; s4 < 4; ++s4) {
            const int seg = g * 4 + s4;                 // row g, cat s4
            const int start = (int)sstart[seg];
            const int pcnt  = (int)(send[seg] - sstart[seg]);
            f32x4 acc = (f32x4){0.f, 0.f, 0.f, 0.f};
            if (pcnt > 0) {
                u16x8 idx = *(const u16x8*)(elist + start);
                for (int e0 = 0; e0 < pcnt; e0 += 8) {
                    const u16x8 nidx = *(const u16x8*)(elist + start + e0 + 8);
                    ushort4 v0 = *(const ushort4*)(Xb + (size_t)idx[0] * 64 + g4);
                    ushort4 v1 = *(const ushort4*)(Xb + (size_t)idx[1] * 64 + g4);
                    ushort4 v2 = *(const ushort4*)(Xb + (size_t)idx[2] * 64 + g4);
                    ushort4 v3 = *(const ushort4*)(Xb + (size_t)idx[3] * 64 + g4);
                    ushort4 v4 = *(const ushort4*)(Xb + (size_t)idx[4] * 64 + g4);
                    ushort4 v5 = *(const ushort4*)(Xb + (size_t)idx[5] * 64 + g4);
                    ushort4 v6 = *(const ushort4*)(Xb + (size_t)idx[6] * 64 + g4);
                    ushort4 v7 = *(const ushort4*)(Xb + (size_t)idx[7] * 64 + g4);
                    acc[0] += bfu2f(v0.x); acc[1] += bfu2f(v0.y); acc[2] += bfu2f(v0.z); acc[3] += bfu2f(v0.w);
                    acc[0] += bfu2f(v1.x); acc[1] += bfu2f(v1.y); acc[2] += bfu2f(v1.z); acc[3] += bfu2f(v1.w);
                    acc[0] += bfu2f(v2.x); acc[1] += bfu2f(v2.y); acc[2] += bfu2f(v2.z); acc[3] += bfu2f(v2.w);
                    acc[0] += bfu2f(v3.x); acc[1] += bfu2f(v3.y); acc[2] += bfu2f(v3.z); acc[3] += bfu2f(v3.w);
                    acc[0] += bfu2f(v4.x); acc[1] += bfu2f(v4.y); acc[2] += bfu2f(v4.z); acc[3] += bfu2f(v4.w);
                    acc[0] += bfu2f(v5.x); acc[1] += bfu2f(v5.y); acc[2] += bfu2f(v5.z); acc[3] += bfu2f(v5.w);
                    acc[0] += bfu2f(v6.x); acc[1] += bfu2f(v6.y); acc[2] += bfu2f(v6.z); acc[3] += bfu2f(v6.w);
                    acc[0] += bfu2f(v7.x); acc[1] += bfu2f(v7.y); acc[2] += bfu2f(v7.z); acc[3] += bfu2f(v7.w);
                    idx = nidx;
                }
            }
            ushort4 o;
            o.x = tobits(acc[0]); o.y = tobits(acc[1]); o.z = tobits(acc[2]); o.w = tobits(acc[3]);
            *(ushort4*)(&Hs[g * 264 + s4 * 64 + g4]) = o;
        }
    }
    __syncthreads();
    // ---- Phase C: 16-wave MFMA + bias + BN + store ------------------------
    const int w = t >> 6, lane = t & 63;
    const int q = lane >> 4, cI = lane & 15;
    const int wr = w & 3;             // row group (16 rows)
    const int wc = w >> 2;            // col group (32 cols)
    f32x4 acc[2];
    #pragma unroll
    for (int i = 0; i < 2; ++i) acc[i] = (f32x4){0.f, 0.f, 0.f, 0.f};
    const unsigned short* arow = &Hs[(wr * 16 + cI) * 264 + q * 8];
    #pragma unroll
    for (int k0 = 0; k0 < 8; ++k0) {
        short8 a = *(const short8*)(arow + k0 * 32);
        #pragma unroll
        for (int t4 = 0; t4 < 2; ++t4) {
            const int t8 = wc * 2 + t4;
            short8 bb = *(const short8*)(Wb + ((size_t)(k0 * 8 + t8) * 64 + lane) * 8);
            acc[t4] = __builtin_amdgcn_mfma_f32_16x16x32_bf16(a, bb, acc[t4], 0, 0, 0);
        }
    }
    __syncthreads();
    const int rloc  = wr * 16 + q * 4;
    const int rbase = n0 + rloc;
    #pragma unroll
    for (int t4 = 0; t4 < 2; ++t4) {
        const int col = (wc * 2 + t4) * 16 + cI;
        const float bc = bias0[col];
        float s = 0.f, qq = 0.f;
        #pragma unroll
        for (int r = 0; r < 4; ++r) {
            float v = acc[t4][r] + bc;
            Hs[(rloc + r) * 136 + col] = tobits(v);
            if (rbase + r >= NN) v = 0.f;
            s += v; qq += v * v;
        }
        s  += __shfl_xor(s, 16, 64);  s  += __shfl_xor(s, 32, 64);
        qq += __shfl_xor(qq, 16, 64); qq += __shfl_xor(qq, 32, 64);
        if (q == 0) { atomicAdd(&psum[col], s); atomicAdd(&psq[col], qq); }
    }
    __syncthreads();
    if (t < 128) { atomicAdd(&stats[t], psum[t]); atomicAdd(&stats[128 + t], psq[t]); }
    {
        const int row  = t >> 4;
        const int col0 = (t & 15) * 8;
        const int grow = n0 + row;
        if (grow < NN) {
            *(ushort4*)(hO + (size_t)grow * 128 + col0)     = *(ushort4*)(&Hs[row * 136 + col0]);
            *(ushort4*)(hO + (size_t)grow * 128 + col0 + 4) = *(ushort4*)(&Hs[row * 136 + col0 + 4]);
        }
    }
}

// ---------------------------------------------------------------------------
// l1_mfma: out = elu(bn(h)) @ W1 + b1; bn-coef computed in preamble.
// ---------------------------------------------------------------------------
__global__ __launch_bounds__(256) void l1_mfma(const void* __restrict__ X,
                                               const void* __restrict__ A,
                                               const unsigned short* __restrict__ hg,
                                               const float* __restrict__ stats,
                                               const void* __restrict__ gamma,
                                               const void* __restrict__ beta,
                                               const unsigned short* __restrict__ Wb1,
                                               const float* __restrict__ bias1,
                                               void* __restrict__ outv) {
    __shared__ unsigned short Es[64 * 136];
    __shared__ float coefL[256];
    __shared__ int dcnt[2];
    int f32f, i64f;
    detect_flags((const unsigned int*)X, (const unsigned int*)A, dcnt, f32f, i64f);
    const int t = threadIdx.x;
    if (t < 128) {
        const float invN = 1.0f / (float)NN;
        const float mean = stats[t] * invN;
        const float var  = stats[128 + t] * invN - mean * mean;
        const float inv  = rsqrtf(var + 1e-5f);
        const float ga = f32f ? ((const float*)gamma)[t] : cvt(((const bf16*)gamma)[t]);
        const float be = f32f ? ((const float*)beta)[t]  : cvt(((const bf16*)beta)[t]);
        const float a = ga * inv;
        coefL[t] = a;
        coefL[128 + t] = be - mean * a;
    }
    __syncthreads();
    const int n0 = blockIdx.x * 64;
    #pragma unroll
    for (int i = 0; i < 8; ++i) {
        const int r = (t >> 5) + i * 8;
        const int k = (t & 31) * 4;
        const int row = n0 + r;
        ushort4 o = make_ushort4(0, 0, 0, 0);
        if (row < NN) {
            ushort4 v = *(const ushort4*)(hg + (size_t)row * 128 + k);
            float f0 = coefL[k + 0] * bfu2f(v.x) + coefL[128 + k + 0];
            float f1 = coefL[k + 1] * bfu2f(v.y) + coefL[128 + k + 1];
            float f2 = coefL[k + 2] * bfu2f(v.z) + coefL[128 + k + 2];
            float f3 = coefL[k + 3] * bfu2f(v.w) + coefL[128 + k + 3];
            f0 = f0 > 0.f ? f0 : expm1f(f0);
            f1 = f1 > 0.f ? f1 : expm1f(f1);
            f2 = f2 > 0.f ? f2 : expm1f(f2);
            f3 = f3 > 0.f ? f3 : expm1f(f3);
            o.x = tobits(f0); o.y = tobits(f1); o.z = tobits(f2); o.w = tobits(f3);
        }
        *(ushort4*)(&Es[r * 136 + k]) = o;
    }
    __syncthreads();
    const int w = t >> 6, lane = t & 63;
    const int q = lane >> 4, cI = lane & 15;
    f32x4 acc[4];
    #pragma unroll
    for (int i = 0; i < 4; ++i) acc[i] = (f32x4){0.f, 0.f, 0.f, 0.f};
    const unsigned short* arow = &Es[(w * 16 + cI) * 136 + q * 8];
    #pragma unroll
    for (int k0 = 0; k0 < 4; ++k0) {
        short8 a = *(const short8*)(arow + k0 * 32);
        #pragma unroll
        for (int t4 = 0; t4 < 4; ++t4) {
            short8 b = *(const short8*)(Wb1 + ((size_t)(k0 * 4 + t4) * 64 + lane) * 8);
            acc[t4] = __builtin_amdgcn_mfma_f32_16x16x32_bf16(a, b, acc[t4], 0, 0, 0);
        }
    }
    __syncthreads();
    float* ot = (float*)Es;                   // 64 x 68 float tile
    const int rloc = w * 16 + q * 4;
    #pragma unroll
    for (int t4 = 0; t4 < 4; ++t4) {
        const int col = t4 * 16 + cI;
        const float bc = bias1[col];
        #pragma unroll
        for (int r = 0; r < 4; ++r)
            ot[(rloc + r) * 68 + col] = acc[t4][r] + bc;
    }
    __syncthreads();
    #pragma unroll
    for (int i = 0; i < 4; ++i) {
        const int m    = t + i * 256;
        const int row  = m >> 4;
        const int col0 = (m & 15) * 4;
        const int grow = n0 + row;
        if (grow >= NN) continue;
        const float f0 = ot[row * 68 + col0 + 0];
        const float f1 = ot[row * 68 + col0 + 1];
        const float f2 = ot[row * 68 + col0 + 2];
        const float f3 = ot[row * 68 + col0 + 3];
        if (f32f) {
            float4 o; o.x = f0; o.y = f1; o.z = f2; o.w = f3;
            *(float4*)((float*)outv + (size_t)grow * 64 + col0) = o;
        } else {
            ushort4 o;
            o.x = tobits(f0); o.y = tobits(f1); o.z = tobits(f2); o.w = tobits(f3);
            *(ushort4*)((unsigned short*)outv + (size_t)grow * 64 + col0) = o;
        }
    }
}

// ---------------------------------------------------------------------------
// Workspace layout (bytes):
//   Xb       : [N+1,64] bf16    @ 0             6,400,256 (row NN = zeros)
//   h        : [N,128]  bf16    @ 6,400,256    12,800,000
//   recs     : [782*8*768] u32  @ 19,200,256   19,218,432
//   stats    : [256] f32        @ 38,418,688        1,024  -- zeroed by memset
//   gcur     : [8192] u32       @ 38,419,712       32,768  -- zeroed by memset
//   Wb       : u16 (Wfold)      @ 38,452,480       65,536
//   Wb1      : u16              @ 38,518,016       16,384
//   bias0    : f32[128]         @ 38,534,400          512
//   bias1    : f32[64]          @ 38,534,912          256
// total 38,535,168 B (~36.7 MiB)
// ---------------------------------------------------------------------------
extern "C" void kernel_launch(void* const* d_in, const int* in_sizes, int n_in,
                              void* d_out, int out_size, void* d_ws, size_t ws_size,
                              hipStream_t stream) {
    const void* A     = d_in[0];
    const void* X     = d_in[1];
    const void* Ws    = d_in[2];
    const void* W0    = d_in[3];
    const void* b0    = d_in[4];
    const void* gamma = d_in[5];
    const void* beta  = d_in[6];
    const void* W1    = d_in[7];
    const void* b1    = d_in[8];

    char* ws = (char*)d_ws;
    unsigned short* Xb       = (unsigned short*)(ws);
    unsigned short* h        = (unsigned short*)(ws + 6400256);
    unsigned int*   recs     = (unsigned int*)  (ws + 19200256);
    float*          stats    = (float*)         (ws + 38418688);
    unsigned int*   gcur     = (unsigned int*)  (ws + 38419712);
    unsigned short* Wb       = (unsigned short*)(ws + 38452480);
    unsigned short* Wb1      = (unsigned short*)(ws + 38518016);
    float*          bias0    = (float*)         (ws + 38534400);
    float*          bias1    = (float*)         (ws + 38534912);

    hipMemsetAsync(stats, 0, 33792, stream);       // stats[256] + gcur[8192]
    fused_kernel<<<NWG + NXB + NPK, 256, 0, stream>>>(X, A, W0, W1, Ws, b0, b1,
                                                      Xb, gcur, recs,
                                                      Wb, Wb1, bias0, bias1);
    l0_mfma     <<<NRB, 1024, 0, stream>>>(gcur, recs, Xb, Wb, bias0, h, stats);
    l1_mfma     <<<NRB, 256, 0, stream>>>(X, A, h, stats, gamma, beta, Wb1, bias1, d_out);
}